// Round 9
// baseline (629.781 us; speedup 1.0000x reference)
//
#include <hip/hip_runtime.h>

// EntityAwareLSTMLayer: B=1024, T=365, DYN=32, STATIC=27, U=256 (3U=768)
// Round 13: FEWER waves. Phase-sum model (step ~ sum of per-wave phase
//   lengths; lockstep barrier serializes LDS/MFMA/VALU phases) fits
//   R7/R9/R12; R9 showed more waves = longer step => go DOWN: 4 waves/WG,
//   1 wave/SIMD, __launch_bounds__(256,1) -> 512-reg budget.
//   - i8 W_hh residual (R12, validated): ALL 48 i8 frags (192 regs) +
//     12 bf16 x-frags (48 regs) register-resident. No streaming, no LDS B.
//   - Per CU/step: ds_reads 40->20 b128, VALU-issue halved, 4-wave barrier.
//     MFMA pipe time unchanged (~1,224 cy) - it becomes the dominant term.
//   - acc-init movs deleted: first MFMA of each chain takes C = loop-
//     invariant FZERO/IZERO; bias+identity added in tail (3 adds/cell).
//   - All 4 A-frag ds_reads issued together at phase start (lgkm pipelining).
//   - Tripwires: WRITE_SIZE >> 1MB = spill; dur > 500us = latency exposure
//     falsifies phase-sum -> revert to 8-wave i8.

typedef short short8 __attribute__((ext_vector_type(8)));
typedef short short4s __attribute__((ext_vector_type(4)));
typedef float f32x4 __attribute__((ext_vector_type(4)));
typedef int   i32x4 __attribute__((ext_vector_type(4)));

#define T_STEPS 365
#define UNITS   256
#define G3      768
#define MROWS   4
#define NWGS    256
#define NTHR    256
#define HP8     288   // A row stride in BYTES (i8); 72 dw == 8 mod 32 -> 2-way free
#define XROW    (T_STEPS * 32)   // 11,680 shorts per batch row
#define WP8_BYTES (256 * G3)     // 196,608: i8 W_hh residual, frag layout

__device__ __forceinline__ unsigned short f2bf(float x) {
    union { float f; unsigned u; } v; v.f = x;
    return (unsigned short)((v.u + 0x7FFFu + ((v.u >> 16) & 1u)) >> 16);
}
__device__ __forceinline__ float sigmoidf_(float x) {
    return 1.0f / (1.0f + __expf(-x));
}
__device__ __forceinline__ float tanhf_(float x) {
    return 1.0f - 2.0f / (1.0f + __expf(2.0f * x));
}
__device__ __forceinline__ float selqf(f32x4 v, int qq) {
    const float a = (qq & 1) ? v[1] : v[0];
    const float b = (qq & 1) ? v[3] : v[2];
    return (qq & 2) ? b : a;
}
__device__ __forceinline__ int selqi(i32x4 v, int qq) {
    const int a = (qq & 1) ? v[1] : v[0];
    const int b = (qq & 1) ? v[3] : v[2];
    return (qq & 2) ? b : a;
}
__device__ __forceinline__ f32x4 MF(short8 a, short8 b, f32x4 c) {
    return __builtin_amdgcn_mfma_f32_16x16x32_bf16(a, b, c, 0, 0, 0);
}
__device__ __forceinline__ i32x4 MI(i32x4 a, i32x4 b, i32x4 c) {
    return __builtin_amdgcn_mfma_i32_16x16x64_i8(a, b, c, 0, 0, 0);
}

// Pack weights (identical to R12, validated):
//  - W_hh residual (k<256) -> i8 frags: (k,n) at wp8[((k>>6)*768+n)*64+(k&63)],
//    value rint(v*1024) clamped to +-127.
//  - W_ih -> bf16 frags: (kx,n) at wpx[((kx>>3)*768+n)*8+(kx&7)]
__global__ __launch_bounds__(256) void pack_weights(
    const float* __restrict__ w_ih, const float* __restrict__ w_hh,
    signed char* __restrict__ wp8, unsigned short* __restrict__ wpx)
{
    int idx = blockIdx.x * 256 + threadIdx.x;
    if (idx < 256 * G3) {
        const int k = idx / G3, n = idx - k * G3;
        float v = w_hh[k * G3 + n];
        if ((n & 255) == k) v -= 1.0f;   // subtract eye3 tile (identity exact in fp32)
        int q = (int)rintf(v * 1024.0f);
        q = q > 127 ? 127 : (q < -127 ? -127 : q);
        wp8[((size_t)((k >> 6) * G3) + n) * 64 + (k & 63)] = (signed char)q;
    } else if (idx < (256 + 32) * G3) {
        const int idx2 = idx - 256 * G3;
        const int kx = idx2 / G3, n = idx2 - kx * G3;
        wpx[((size_t)((kx >> 3) * G3) + n) * 8 + (kx & 7)] = f2bf(w_ih[kx * G3 + n]);
    }
}

__global__ __launch_bounds__(NTHR, 1) void lstm_mfma(
    const float* __restrict__ x_dyn,   // [1024][365][32]
    const float* __restrict__ x_sta,   // [1024][27]
    const signed char* __restrict__ wp8,    // i8 W_hh residual frags
    const unsigned short* __restrict__ wpx, // bf16 W_ih frags
    const float* __restrict__ w_sh,    // [27][256]
    const float* __restrict__ bias,    // [768]
    const float* __restrict__ bias_s,  // [256]
    float* __restrict__ out)           // [1024][256]
{
    __shared__ signed char A_s[2][MROWS][HP8];   // 2,304 B (h as i8, dbuf)
    __shared__ unsigned short xs[MROWS * XROW];  // 93,440 B (all x, bf16)

    const int tid  = threadIdx.x;
    const int b0   = blockIdx.x * MROWS;
    const int lane = tid & 63;
    const int wv   = tid >> 6;          // wave 0..3, owns units wv*64..+63
    const int mm   = lane & 15;
    const int qq   = lane >> 4;

    // ---- ALL W_hh residual frags resident: 4 ks x 3 gates x 4 halves ----
    // 48 i8 frags = 192 regs; 12 bf16 x-frags = 48 regs. Budget 512 (1 wave/SIMD).
    i32x4 bwi[4][3][4];
    #pragma unroll
    for (int ks = 0; ks < 4; ++ks)
        #pragma unroll
        for (int g = 0; g < 3; ++g)
            #pragma unroll
            for (int h = 0; h < 4; ++h) {
                const int n = g * UNITS + wv * 64 + h * 16 + mm;
                bwi[ks][g][h] = *(const i32x4*)(wp8 +
                    ((size_t)(ks * G3) + n) * 64 + qq * 16);
            }
    short8 bwx[3][4];
    #pragma unroll
    for (int g = 0; g < 3; ++g)
        #pragma unroll
        for (int h = 0; h < 4; ++h) {
            const int n = g * UNITS + wv * 64 + h * 16 + mm;
            bwx[g][h] = *(const short8*)(wpx + ((size_t)(qq * G3) + n) * 8);
        }

    // ---- pre-stage ALL x for this WG's 4 batch rows (fp32 -> bf16) ----
    #pragma unroll
    for (int r = 0; r < MROWS; ++r) {
        const float4* src = (const float4*)(x_dyn + (size_t)(b0 + r) * XROW);
        short4s* dst = (short4s*)(xs + r * XROW);
        for (int i = tid; i < XROW / 4; i += NTHR) {
            const float4 v = src[i];
            short4s w;
            w.x = (short)f2bf(v.x); w.y = (short)f2bf(v.y);
            w.z = (short)f2bf(v.z); w.w = (short)f2bf(v.w);
            dst[i] = w;
        }
    }
    // zero both h buffers (h must be 0 at t=0)
    {
        int* az = (int*)A_s;
        for (int i = tid; i < 2 * MROWS * HP8 / 4; i += NTHR) az[i] = 0;
    }
    __syncthreads();

    // ---- cell mapping: lane (mm,qq) owns 4 cells (batch row qq, units
    //      u(h) = wv*64 + h*16 + mm, h=0..3) via acc elem qq ----
    float bfv[4], bov[4], bgv[4], ig[4], cc[4], hp[4];
    #pragma unroll
    for (int h = 0; h < 4; ++h) {
        const int u = wv * 64 + h * 16 + mm;
        bfv[h] = bias[u];
        bov[h] = bias[UNITS + u];
        bgv[h] = bias[2 * UNITS + u];
        float s = bias_s[u];
        #pragma unroll
        for (int j = 0; j < 27; ++j)
            s += x_sta[(b0 + qq) * 27 + j] * w_sh[j * UNITS + u];
        ig[h] = sigmoidf_(s);
        cc[h] = 0.0f; hp[h] = 0.0f;
    }

    const int arow  = (mm & 3);          // dedup: quads broadcast-read same 4 rows
    const int abase = arow * HP8 + qq * 16;
    const unsigned short* xp = xs + (size_t)arow * XROW + qq * 8;
    const float SCL = 1.0f / (127.0f * 1024.0f);
    const f32x4 FZERO = {0.f, 0.f, 0.f, 0.f};
    const i32x4 IZERO = {0, 0, 0, 0};

    // prefetch x-fragment for t=0
    short8 xa = *(const short8*)(xp);

    for (int t = 0; t < T_STEPS; ++t) {
        const int p = t & 1;
        __syncthreads();   // A[p] h complete; A[p^1] free. No vmem in flight.

        const signed char* Ap = &A_s[p][0][0];

        // issue all 4 A-frag reads together (compiler pipelines lgkmcnt)
        const i32x4 a0 = *(const i32x4*)(Ap + abase);
        const i32x4 a1 = *(const i32x4*)(Ap + abase + 64);
        const i32x4 a2 = *(const i32x4*)(Ap + abase + 128);
        const i32x4 a3 = *(const i32x4*)(Ap + abase + 192);

        // x-contribution: first MFMA defines each float acc (C = FZERO)
        f32x4 acf[4], aco[4], acg[4];
        #pragma unroll
        for (int h = 0; h < 4; ++h) {
            acf[h] = MF(xa, bwx[0][h], FZERO);
            aco[h] = MF(xa, bwx[1][h], FZERO);
            acg[h] = MF(xa, bwx[2][h], FZERO);
        }
        // h @ R in i8: ks=0 defines int accs (C = IZERO), ks=1..3 accumulate
        i32x4 aif[4], aio[4], aig[4];
        #pragma unroll
        for (int h = 0; h < 4; ++h) {
            aif[h] = MI(a0, bwi[0][0][h], IZERO);
            aio[h] = MI(a0, bwi[0][1][h], IZERO);
            aig[h] = MI(a0, bwi[0][2][h], IZERO);
        }
        #pragma unroll
        for (int h = 0; h < 4; ++h) {
            aif[h] = MI(a1, bwi[1][0][h], aif[h]);
            aio[h] = MI(a1, bwi[1][1][h], aio[h]);
            aig[h] = MI(a1, bwi[1][2][h], aig[h]);
        }
        #pragma unroll
        for (int h = 0; h < 4; ++h) {
            aif[h] = MI(a2, bwi[2][0][h], aif[h]);
            aio[h] = MI(a2, bwi[2][1][h], aio[h]);
            aig[h] = MI(a2, bwi[2][2][h], aig[h]);
        }
        #pragma unroll
        for (int h = 0; h < 4; ++h) {
            aif[h] = MI(a3, bwi[3][0][h], aif[h]);
            aio[h] = MI(a3, bwi[3][1][h], aio[h]);
            aig[h] = MI(a3, bwi[3][2][h], aig[h]);
        }

        // prefetch next step's x-fragment (hides under the tail)
        {
            const int tn = (t + 1 < T_STEPS) ? t + 1 : t;
            xa = *(const short8*)(xp + (size_t)tn * 32);
        }

        // ---- cell updates: acc elem qq IS this lane's cell ----
        #pragma unroll
        for (int h = 0; h < 4; ++h) {
            const float bh  = hp[h];   // exact fp32 identity term
            const float gfv = selqf(acf[h], qq) + bfv[h] + bh
                            + (float)selqi(aif[h], qq) * SCL;
            const float gov = selqf(aco[h], qq) + bov[h] + bh
                            + (float)selqi(aio[h], qq) * SCL;
            const float ggv = selqf(acg[h], qq) + bgv[h] + bh
                            + (float)selqi(aig[h], qq) * SCL;
            const float f   = sigmoidf_(gfv);
            const float o   = sigmoidf_(gov);
            const float gt  = tanhf_(ggv);
            const float cn  = f * cc[h] + ig[h] * gt;
            cc[h] = cn;
            const float hn  = o * tanhf_(cn);
            hp[h] = hn;
            const int q = __float2int_rn(hn * 127.0f);   // |hn|<=1 -> |q|<=127
            A_s[p ^ 1][qq][wv * 64 + h * 16 + mm] = (signed char)q;
        }
    }

    #pragma unroll
    for (int h = 0; h < 4; ++h)
        out[(size_t)(b0 + qq) * UNITS + (wv * 64 + h * 16 + mm)] = hp[h];
}

extern "C" void kernel_launch(void* const* d_in, const int* in_sizes, int n_in,
                              void* d_out, int out_size, void* d_ws, size_t ws_size,
                              hipStream_t stream) {
    const float* x_dyn  = (const float*)d_in[0];
    const float* x_sta  = (const float*)d_in[1];
    const float* w_ih   = (const float*)d_in[2];
    const float* w_hh   = (const float*)d_in[3];
    const float* w_sh   = (const float*)d_in[4];
    const float* bias   = (const float*)d_in[5];
    const float* bias_s = (const float*)d_in[6];
    float* out = (float*)d_out;
    signed char* wp8 = (signed char*)d_ws;                            // 196,608 B
    unsigned short* wpx = (unsigned short*)((char*)d_ws + WP8_BYTES); //  49,152 B

    pack_weights<<<((256 + 32) * G3 + 255) / 256, 256, 0, stream>>>(w_ih, w_hh, wp8, wpx);
    lstm_mfma<<<NWGS, NTHR, 0, stream>>>(x_dyn, x_sta, wp8, wpx, w_sh, bias, bias_s, out);
}

// Round 10
// 471.552 us; speedup vs baseline: 1.3356x; 1.3356x over previous
//
#include <hip/hip_runtime.h>

// EntityAwareLSTMLayer: B=1024, T=365, DYN=32, STATIC=27, U=256 (3U=768)
// Round 14: pipeline the exposed region of R12 (474us base, the proven opt).
//   Occupancy scan closed: 1/SIMD=629, 2/SIMD=474, 4/SIMD=816 -> keep 2.
//   Step ~3,100cy: matrix 1,212 (locked), VALU ~700, LDS ~500, exposed ~650.
//   - x-MFMAs for step t+1 issued during step t (x independent of h):
//     ping-pong FA/FB float-acc sets, unroll-2, no copies. Removes 6 MFMAs
//     from the post-barrier critical path; fills matrix pipe during tail.
//   - First MFMA of each chain takes C=FZERO/IZERO (kills ~24 movs/step).
//   - h0's 12 i8 MFMAs complete before h1's -> tail(h0) overlaps h1 matrix.
//   - bias+identity applied in tail (cannot fold a step early).
//   - Tripwires: WRITE_SIZE >> 1MB = spill (drop FB set); absmax 0.0078.

typedef short short8 __attribute__((ext_vector_type(8)));
typedef short short4s __attribute__((ext_vector_type(4)));
typedef float f32x4 __attribute__((ext_vector_type(4)));
typedef int   i32x4 __attribute__((ext_vector_type(4)));

#define T_STEPS 365
#define UNITS   256
#define G3      768
#define MROWS   4
#define NWGS    256
#define HP8     288   // A row stride in BYTES (i8); 72 dw == 8 mod 32 -> 2-way free
#define XROW    (T_STEPS * 32)   // 11,680 shorts per batch row
#define WP8_BYTES (256 * G3)     // 196,608: i8 W_hh residual frags

__device__ __forceinline__ unsigned short f2bf(float x) {
    union { float f; unsigned u; } v; v.f = x;
    return (unsigned short)((v.u + 0x7FFFu + ((v.u >> 16) & 1u)) >> 16);
}
__device__ __forceinline__ float sigmoidf_(float x) {
    return 1.0f / (1.0f + __expf(-x));
}
__device__ __forceinline__ float tanhf_(float x) {
    return 1.0f - 2.0f / (1.0f + __expf(2.0f * x));
}
__device__ __forceinline__ float selqf(f32x4 v, int qq) {
    const float a = (qq & 1) ? v[1] : v[0];
    const float b = (qq & 1) ? v[3] : v[2];
    return (qq & 2) ? b : a;
}
__device__ __forceinline__ int selqi(i32x4 v, int qq) {
    const int a = (qq & 1) ? v[1] : v[0];
    const int b = (qq & 1) ? v[3] : v[2];
    return (qq & 2) ? b : a;
}
__device__ __forceinline__ f32x4 MF(short8 a, short8 b, f32x4 c) {
    return __builtin_amdgcn_mfma_f32_16x16x32_bf16(a, b, c, 0, 0, 0);
}
__device__ __forceinline__ i32x4 MI(i32x4 a, i32x4 b, i32x4 c) {
    return __builtin_amdgcn_mfma_i32_16x16x64_i8(a, b, c, 0, 0, 0);
}

// Pack weights (identical to R12, validated):
//  - W_hh residual (k<256) -> i8 frags: (k,n) at wp8[((k>>6)*768+n)*64+(k&63)],
//    value rint(v*1024) clamped to +-127.
//  - W_ih -> bf16 frags: (kx,n) at wpx[((kx>>3)*768+n)*8+(kx&7)]
__global__ __launch_bounds__(256) void pack_weights(
    const float* __restrict__ w_ih, const float* __restrict__ w_hh,
    signed char* __restrict__ wp8, unsigned short* __restrict__ wpx)
{
    int idx = blockIdx.x * 256 + threadIdx.x;
    if (idx < 256 * G3) {
        const int k = idx / G3, n = idx - k * G3;
        float v = w_hh[k * G3 + n];
        if ((n & 255) == k) v -= 1.0f;   // subtract eye3 tile (identity exact in fp32)
        int q = (int)rintf(v * 1024.0f);
        q = q > 127 ? 127 : (q < -127 ? -127 : q);
        wp8[((size_t)((k >> 6) * G3) + n) * 64 + (k & 63)] = (signed char)q;
    } else if (idx < (256 + 32) * G3) {
        const int idx2 = idx - 256 * G3;
        const int kx = idx2 / G3, n = idx2 - kx * G3;
        wpx[((size_t)((kx >> 3) * G3) + n) * 8 + (kx & 7)] = f2bf(w_ih[kx * G3 + n]);
    }
}

// One timestep. FC = float accs for THIS step (x part, computed last step);
// FN = float accs for NEXT step (computed here while tail runs). DONEXT is a
// compile-time literal at each expansion.
#define STEP_BODY(T, FC, FN, DONEXT) do {                                     \
    const int p_ = (T) & 1;                                                   \
    __syncthreads();                                                          \
    const signed char* Ap_ = &A_s[p_][0][0];                                  \
    const i32x4 a0_ = *(const i32x4*)(Ap_ + abase);                           \
    const i32x4 a1_ = *(const i32x4*)(Ap_ + abase + 64);                      \
    const i32x4 a2_ = *(const i32x4*)(Ap_ + abase + 128);                     \
    const i32x4 a3_ = *(const i32x4*)(Ap_ + abase + 192);                     \
    /* h=0 chains complete first -> tail(h0) overlaps h1's matrix burst */    \
    i32x4 if0_ = MI(a0_, bwi[0][0][0], IZERO);                                \
    i32x4 io0_ = MI(a0_, bwi[0][1][0], IZERO);                                \
    i32x4 ig0_ = MI(a0_, bwi[0][2][0], IZERO);                                \
    if0_ = MI(a1_, bwi[1][0][0], if0_);                                       \
    io0_ = MI(a1_, bwi[1][1][0], io0_);                                       \
    ig0_ = MI(a1_, bwi[1][2][0], ig0_);                                       \
    if0_ = MI(a2_, bwi[2][0][0], if0_);                                       \
    io0_ = MI(a2_, bwi[2][1][0], io0_);                                       \
    ig0_ = MI(a2_, bwi[2][2][0], ig0_);                                       \
    if0_ = MI(a3_, bwi[3][0][0], if0_);                                       \
    io0_ = MI(a3_, bwi[3][1][0], io0_);                                       \
    ig0_ = MI(a3_, bwi[3][2][0], ig0_);                                       \
    i32x4 if1_ = MI(a0_, bwi[0][0][1], IZERO);                                \
    i32x4 io1_ = MI(a0_, bwi[0][1][1], IZERO);                                \
    i32x4 ig1_ = MI(a0_, bwi[0][2][1], IZERO);                                \
    if1_ = MI(a1_, bwi[1][0][1], if1_);                                       \
    io1_ = MI(a1_, bwi[1][1][1], io1_);                                       \
    ig1_ = MI(a1_, bwi[1][2][1], ig1_);                                       \
    if1_ = MI(a2_, bwi[2][0][1], if1_);                                       \
    io1_ = MI(a2_, bwi[2][1][1], io1_);                                       \
    ig1_ = MI(a2_, bwi[2][2][1], ig1_);                                       \
    if1_ = MI(a3_, bwi[3][0][1], if1_);                                       \
    io1_ = MI(a3_, bwi[3][1][1], io1_);                                       \
    ig1_ = MI(a3_, bwi[3][2][1], ig1_);                                       \
    if (DONEXT) {                                                             \
        /* x-part of step T+1: fills matrix pipe during the tails below */    \
        const short8 xu_ = xa;                                                \
        FN[0] = MF(xu_, bwx[0][0], FZERO);                                    \
        FN[1] = MF(xu_, bwx[1][0], FZERO);                                    \
        FN[2] = MF(xu_, bwx[2][0], FZERO);                                    \
        FN[3] = MF(xu_, bwx[0][1], FZERO);                                    \
        FN[4] = MF(xu_, bwx[1][1], FZERO);                                    \
        FN[5] = MF(xu_, bwx[2][1], FZERO);                                    \
        const int tn_ = ((T) + 2 < T_STEPS) ? (T) + 2 : T_STEPS - 1;          \
        xa = *(const short8*)(xp + (size_t)tn_ * 32);                         \
    }                                                                         \
    {   /* tail h=0 */                                                        \
        const float bh_ = hp[0];                                              \
        const float gf_ = selqf(FC[0], qq) + bfv[0] + bh_                     \
                        + (float)selqi(if0_, qq) * SCL;                       \
        const float go_ = selqf(FC[1], qq) + bov[0] + bh_                     \
                        + (float)selqi(io0_, qq) * SCL;                       \
        const float gg_ = selqf(FC[2], qq) + bgv[0] + bh_                     \
                        + (float)selqi(ig0_, qq) * SCL;                       \
        const float f_  = sigmoidf_(gf_);                                     \
        const float o_  = sigmoidf_(go_);                                     \
        const float gt_ = tanhf_(gg_);                                        \
        const float cn_ = f_ * cc[0] + ig[0] * gt_;                           \
        cc[0] = cn_;                                                          \
        const float hn_ = o_ * tanhf_(cn_);                                   \
        hp[0] = hn_;                                                          \
        A_s[p_ ^ 1][qq][u0] = (signed char)__float2int_rn(hn_ * 127.0f);      \
    }                                                                         \
    {   /* tail h=1 */                                                        \
        const float bh_ = hp[1];                                              \
        const float gf_ = selqf(FC[3], qq) + bfv[1] + bh_                     \
                        + (float)selqi(if1_, qq) * SCL;                       \
        const float go_ = selqf(FC[4], qq) + bov[1] + bh_                     \
                        + (float)selqi(io1_, qq) * SCL;                       \
        const float gg_ = selqf(FC[5], qq) + bgv[1] + bh_                     \
                        + (float)selqi(ig1_, qq) * SCL;                       \
        const float f_  = sigmoidf_(gf_);                                     \
        const float o_  = sigmoidf_(go_);                                     \
        const float gt_ = tanhf_(gg_);                                        \
        const float cn_ = f_ * cc[1] + ig[1] * gt_;                           \
        cc[1] = cn_;                                                          \
        const float hn_ = o_ * tanhf_(cn_);                                   \
        hp[1] = hn_;                                                          \
        A_s[p_ ^ 1][qq][u1] = (signed char)__float2int_rn(hn_ * 127.0f);      \
    }                                                                         \
} while (0)

__global__ __launch_bounds__(512, 2) void lstm_mfma(
    const float* __restrict__ x_dyn,   // [1024][365][32]
    const float* __restrict__ x_sta,   // [1024][27]
    const signed char* __restrict__ wp8,    // i8 W_hh residual frags
    const unsigned short* __restrict__ wpx, // bf16 W_ih frags
    const float* __restrict__ w_sh,    // [27][256]
    const float* __restrict__ bias,    // [768]
    const float* __restrict__ bias_s,  // [256]
    float* __restrict__ out)           // [1024][256]
{
    __shared__ signed char A_s[2][MROWS][HP8];   // 2,304 B (h as i8, dbuf)
    __shared__ unsigned short xs[MROWS * XROW];  // 93,440 B (all x, bf16)

    const int tid  = threadIdx.x;
    const int b0   = blockIdx.x * MROWS;
    const int lane = tid & 63;
    const int wv   = tid >> 6;          // wave 0..7, owns units wv*32..+31
    const int mm   = lane & 15;
    const int qq   = lane >> 4;

    // ---- W_hh residual frags resident: 4 ks x 3 gates x 2 halves = 96 regs ----
    i32x4 bwi[4][3][2];
    #pragma unroll
    for (int ks = 0; ks < 4; ++ks)
        #pragma unroll
        for (int g = 0; g < 3; ++g)
            #pragma unroll
            for (int h = 0; h < 2; ++h) {
                const int n = g * UNITS + wv * 32 + h * 16 + mm;
                bwi[ks][g][h] = *(const i32x4*)(wp8 +
                    ((size_t)(ks * G3) + n) * 64 + qq * 16);
            }
    short8 bwx[3][2];
    #pragma unroll
    for (int g = 0; g < 3; ++g)
        #pragma unroll
        for (int h = 0; h < 2; ++h)
            bwx[g][h] = *(const short8*)(wpx +
                ((size_t)(qq * G3) + g * UNITS + wv * 32 + h * 16 + mm) * 8);

    // ---- pre-stage ALL x for this WG's 4 batch rows (fp32 -> bf16) ----
    #pragma unroll
    for (int r = 0; r < MROWS; ++r) {
        const float4* src = (const float4*)(x_dyn + (size_t)(b0 + r) * XROW);
        short4s* dst = (short4s*)(xs + r * XROW);
        for (int i = tid; i < XROW / 4; i += 512) {
            const float4 v = src[i];
            short4s w;
            w.x = (short)f2bf(v.x); w.y = (short)f2bf(v.y);
            w.z = (short)f2bf(v.z); w.w = (short)f2bf(v.w);
            dst[i] = w;
        }
    }
    // zero both h buffers (h must be 0 at t=0)
    {
        int* az = (int*)A_s;
        for (int i = tid; i < 2 * MROWS * HP8 / 4; i += 512) az[i] = 0;
    }
    __syncthreads();

    // ---- cell mapping: lane (mm,qq) owns cells (batch row qq, units u0,u1) ----
    const int u0 = wv * 32 + mm;
    const int u1 = u0 + 16;

    const float bfv[2] = { bias[u0],             bias[u1] };
    const float bov[2] = { bias[UNITS + u0],     bias[UNITS + u1] };
    const float bgv[2] = { bias[2 * UNITS + u0], bias[2 * UNITS + u1] };

    float ig[2], cc[2], hp[2];
    #pragma unroll
    for (int h = 0; h < 2; ++h) {
        const int u = h ? u1 : u0;
        float s = bias_s[u];
        #pragma unroll
        for (int j = 0; j < 27; ++j)
            s += x_sta[(b0 + qq) * 27 + j] * w_sh[j * UNITS + u];
        ig[h] = sigmoidf_(s);
        cc[h] = 0.0f; hp[h] = 0.0f;
    }

    const int arow  = (mm & 3);          // dedup: quads broadcast-read same 4 rows
    const int abase = arow * HP8 + qq * 16;
    const unsigned short* xp = xs + (size_t)arow * XROW + qq * 8;
    const float SCL = 1.0f / (127.0f * 1024.0f);
    const f32x4 FZERO = {0.f, 0.f, 0.f, 0.f};
    const i32x4 IZERO = {0, 0, 0, 0};

    // ---- prologue: x-part of step 0 into FA; prefetch x(1) ----
    f32x4 FA[6], FB[6];
    short8 xa;
    {
        const short8 x0 = *(const short8*)(xp);
        FA[0] = MF(x0, bwx[0][0], FZERO);
        FA[1] = MF(x0, bwx[1][0], FZERO);
        FA[2] = MF(x0, bwx[2][0], FZERO);
        FA[3] = MF(x0, bwx[0][1], FZERO);
        FA[4] = MF(x0, bwx[1][1], FZERO);
        FA[5] = MF(x0, bwx[2][1], FZERO);
        xa = *(const short8*)(xp + 32);   // x(1)
    }

    // 365 steps = 182 unrolled pairs + final step (uses FA, no next)
    for (int i = 0; i < 182; ++i) {
        STEP_BODY(2 * i,     FA, FB, true);
        STEP_BODY(2 * i + 1, FB, FA, true);
    }
    STEP_BODY(364, FA, FB, false);

    out[(size_t)(b0 + qq) * UNITS + u0] = hp[0];
    out[(size_t)(b0 + qq) * UNITS + u1] = hp[1];
}

extern "C" void kernel_launch(void* const* d_in, const int* in_sizes, int n_in,
                              void* d_out, int out_size, void* d_ws, size_t ws_size,
                              hipStream_t stream) {
    const float* x_dyn  = (const float*)d_in[0];
    const float* x_sta  = (const float*)d_in[1];
    const float* w_ih   = (const float*)d_in[2];
    const float* w_hh   = (const float*)d_in[3];
    const float* w_sh   = (const float*)d_in[4];
    const float* bias   = (const float*)d_in[5];
    const float* bias_s = (const float*)d_in[6];
    float* out = (float*)d_out;
    signed char* wp8 = (signed char*)d_ws;                            // 196,608 B
    unsigned short* wpx = (unsigned short*)((char*)d_ws + WP8_BYTES); //  49,152 B

    pack_weights<<<((256 + 32) * G3 + 255) / 256, 256, 0, stream>>>(w_ih, w_hh, wp8, wpx);
    lstm_mfma<<<NWGS, 512, 0, stream>>>(x_dyn, x_sta, wp8, wpx, w_sh, bias, bias_s, out);
}

// Round 11
// 369.700 us; speedup vs baseline: 1.7035x; 1.2755x over previous
//
#include <hip/hip_runtime.h>

// EntityAwareLSTMLayer: B=1024, T=365, DYN=32, STATIC=27, U=256 (3U=768)
// Round 15: delete the VALU fat in the tail (the ~1,000cy non-MFMA VALU
//   phase, now the biggest attackable term; matrix is structurally locked).
//   - selq DELETED via A-row remap: arow = mm>>2 (A rows grouped per batch)
//     -> C rows 4qq..4qq+3 all hold batch qq -> all 4 acc elements identical
//     -> use element 0. Saves 24 v_cndmask/lane/step; same LDS address set
//     (still broadcast + 2-way, 0 conflicts); same MFMA count.
//   - IEEE div -> v_rcp_f32 (asm): sigmoid = rcp(1+e^-x), tanh = 1-2*rcp(1+e^2x).
//     NaN-safe (rcp(inf)=0 saturates identically). ~6 ops saved per divide,
//     8 divides/lane/step. ~1e-6 rel err, absmax unchanged.
//   - Everything else = R14 (i8 W_hh, x-part FA/FB pipeline, 2 waves/SIMD).

typedef short short8 __attribute__((ext_vector_type(8)));
typedef short short4s __attribute__((ext_vector_type(4)));
typedef float f32x4 __attribute__((ext_vector_type(4)));
typedef int   i32x4 __attribute__((ext_vector_type(4)));

#define T_STEPS 365
#define UNITS   256
#define G3      768
#define MROWS   4
#define NWGS    256
#define HP8     288   // A row stride in BYTES (i8); 72 dw == 8 mod 32 -> 2-way free
#define XROW    (T_STEPS * 32)   // 11,680 shorts per batch row
#define WP8_BYTES (256 * G3)     // 196,608: i8 W_hh residual frags

__device__ __forceinline__ unsigned short f2bf(float x) {
    union { float f; unsigned u; } v; v.f = x;
    return (unsigned short)((v.u + 0x7FFFu + ((v.u >> 16) & 1u)) >> 16);
}
__device__ __forceinline__ float rcp_(float x) {
    float r; asm("v_rcp_f32 %0, %1" : "=v"(r) : "v"(x)); return r;
}
__device__ __forceinline__ float sigm_(float x) {      // rcp(1+e^-x); rcp(inf)=0
    return rcp_(1.0f + __expf(-x));
}
__device__ __forceinline__ float tanh_(float x) {      // 1-2*rcp(1+e^2x)
    return 1.0f - 2.0f * rcp_(1.0f + __expf(2.0f * x));
}
__device__ __forceinline__ f32x4 MF(short8 a, short8 b, f32x4 c) {
    return __builtin_amdgcn_mfma_f32_16x16x32_bf16(a, b, c, 0, 0, 0);
}
__device__ __forceinline__ i32x4 MI(i32x4 a, i32x4 b, i32x4 c) {
    return __builtin_amdgcn_mfma_i32_16x16x64_i8(a, b, c, 0, 0, 0);
}

// Pack weights (identical to R12/R14, validated):
//  - W_hh residual (k<256) -> i8 frags: (k,n) at wp8[((k>>6)*768+n)*64+(k&63)],
//    value rint(v*1024) clamped to +-127.
//  - W_ih -> bf16 frags: (kx,n) at wpx[((kx>>3)*768+n)*8+(kx&7)]
__global__ __launch_bounds__(256) void pack_weights(
    const float* __restrict__ w_ih, const float* __restrict__ w_hh,
    signed char* __restrict__ wp8, unsigned short* __restrict__ wpx)
{
    int idx = blockIdx.x * 256 + threadIdx.x;
    if (idx < 256 * G3) {
        const int k = idx / G3, n = idx - k * G3;
        float v = w_hh[k * G3 + n];
        if ((n & 255) == k) v -= 1.0f;   // subtract eye3 tile (identity exact in fp32)
        int q = (int)rintf(v * 1024.0f);
        q = q > 127 ? 127 : (q < -127 ? -127 : q);
        wp8[((size_t)((k >> 6) * G3) + n) * 64 + (k & 63)] = (signed char)q;
    } else if (idx < (256 + 32) * G3) {
        const int idx2 = idx - 256 * G3;
        const int kx = idx2 / G3, n = idx2 - kx * G3;
        wpx[((size_t)((kx >> 3) * G3) + n) * 8 + (kx & 7)] = f2bf(w_ih[kx * G3 + n]);
    }
}

// One timestep. FC = float accs for THIS step (x part, computed last step);
// FN = float accs for NEXT step. All acc elements are identical (A-row
// grouping) -> element 0 is this lane's cell (batch qq).
#define STEP_BODY(T, FC, FN, DONEXT) do {                                     \
    const int p_ = (T) & 1;                                                   \
    __syncthreads();                                                          \
    const signed char* Ap_ = &A_s[p_][0][0];                                  \
    const i32x4 a0_ = *(const i32x4*)(Ap_ + abase);                           \
    const i32x4 a1_ = *(const i32x4*)(Ap_ + abase + 64);                      \
    const i32x4 a2_ = *(const i32x4*)(Ap_ + abase + 128);                     \
    const i32x4 a3_ = *(const i32x4*)(Ap_ + abase + 192);                     \
    /* h=0 chains complete first -> tail(h0) overlaps h1's matrix burst */    \
    i32x4 if0_ = MI(a0_, bwi[0][0][0], IZERO);                                \
    i32x4 io0_ = MI(a0_, bwi[0][1][0], IZERO);                                \
    i32x4 ig0_ = MI(a0_, bwi[0][2][0], IZERO);                                \
    if0_ = MI(a1_, bwi[1][0][0], if0_);                                       \
    io0_ = MI(a1_, bwi[1][1][0], io0_);                                       \
    ig0_ = MI(a1_, bwi[1][2][0], ig0_);                                       \
    if0_ = MI(a2_, bwi[2][0][0], if0_);                                       \
    io0_ = MI(a2_, bwi[2][1][0], io0_);                                       \
    ig0_ = MI(a2_, bwi[2][2][0], ig0_);                                       \
    if0_ = MI(a3_, bwi[3][0][0], if0_);                                       \
    io0_ = MI(a3_, bwi[3][1][0], io0_);                                       \
    ig0_ = MI(a3_, bwi[3][2][0], ig0_);                                       \
    i32x4 if1_ = MI(a0_, bwi[0][0][1], IZERO);                                \
    i32x4 io1_ = MI(a0_, bwi[0][1][1], IZERO);                                \
    i32x4 ig1_ = MI(a0_, bwi[0][2][1], IZERO);                                \
    if1_ = MI(a1_, bwi[1][0][1], if1_);                                       \
    io1_ = MI(a1_, bwi[1][1][1], io1_);                                       \
    ig1_ = MI(a1_, bwi[1][2][1], ig1_);                                       \
    if1_ = MI(a2_, bwi[2][0][1], if1_);                                       \
    io1_ = MI(a2_, bwi[2][1][1], io1_);                                       \
    ig1_ = MI(a2_, bwi[2][2][1], ig1_);                                       \
    if1_ = MI(a3_, bwi[3][0][1], if1_);                                       \
    io1_ = MI(a3_, bwi[3][1][1], io1_);                                       \
    ig1_ = MI(a3_, bwi[3][2][1], ig1_);                                       \
    if (DONEXT) {                                                             \
        /* x-part of step T+1: fills matrix pipe during the tails below */    \
        const short8 xu_ = xa;                                                \
        FN[0] = MF(xu_, bwx[0][0], FZERO);                                    \
        FN[1] = MF(xu_, bwx[1][0], FZERO);                                    \
        FN[2] = MF(xu_, bwx[2][0], FZERO);                                    \
        FN[3] = MF(xu_, bwx[0][1], FZERO);                                    \
        FN[4] = MF(xu_, bwx[1][1], FZERO);                                    \
        FN[5] = MF(xu_, bwx[2][1], FZERO);                                    \
        const int tn_ = ((T) + 2 < T_STEPS) ? (T) + 2 : T_STEPS - 1;          \
        xa = *(const short8*)(xp + (size_t)tn_ * 32);                         \
    }                                                                         \
    {   /* tail h=0: element 0 of each acc (no selects) */                    \
        const float bh_ = hp[0];                                              \
        const float gf_ = FC[0][0] + bfv[0] + bh_ + (float)if0_[0] * SCL;     \
        const float go_ = FC[1][0] + bov[0] + bh_ + (float)io0_[0] * SCL;     \
        const float gg_ = FC[2][0] + bgv[0] + bh_ + (float)ig0_[0] * SCL;     \
        const float f_  = sigm_(gf_);                                         \
        const float o_  = sigm_(go_);                                         \
        const float gt_ = tanh_(gg_);                                         \
        const float cn_ = f_ * cc[0] + ig[0] * gt_;                           \
        cc[0] = cn_;                                                          \
        const float hn_ = o_ * tanh_(cn_);                                    \
        hp[0] = hn_;                                                          \
        A_s[p_ ^ 1][qq][u0] = (signed char)__float2int_rn(hn_ * 127.0f);      \
    }                                                                         \
    {   /* tail h=1 */                                                        \
        const float bh_ = hp[1];                                              \
        const float gf_ = FC[3][0] + bfv[1] + bh_ + (float)if1_[0] * SCL;     \
        const float go_ = FC[4][0] + bov[1] + bh_ + (float)io1_[0] * SCL;     \
        const float gg_ = FC[5][0] + bgv[1] + bh_ + (float)ig1_[0] * SCL;     \
        const float f_  = sigm_(gf_);                                         \
        const float o_  = sigm_(go_);                                         \
        const float gt_ = tanh_(gg_);                                         \
        const float cn_ = f_ * cc[1] + ig[1] * gt_;                           \
        cc[1] = cn_;                                                          \
        const float hn_ = o_ * tanh_(cn_);                                    \
        hp[1] = hn_;                                                          \
        A_s[p_ ^ 1][qq][u1] = (signed char)__float2int_rn(hn_ * 127.0f);      \
    }                                                                         \
} while (0)

__global__ __launch_bounds__(512, 2) void lstm_mfma(
    const float* __restrict__ x_dyn,   // [1024][365][32]
    const float* __restrict__ x_sta,   // [1024][27]
    const signed char* __restrict__ wp8,    // i8 W_hh residual frags
    const unsigned short* __restrict__ wpx, // bf16 W_ih frags
    const float* __restrict__ w_sh,    // [27][256]
    const float* __restrict__ bias,    // [768]
    const float* __restrict__ bias_s,  // [256]
    float* __restrict__ out)           // [1024][256]
{
    __shared__ signed char A_s[2][MROWS][HP8];   // 2,304 B (h as i8, dbuf)
    __shared__ unsigned short xs[MROWS * XROW];  // 93,440 B (all x, bf16)

    const int tid  = threadIdx.x;
    const int b0   = blockIdx.x * MROWS;
    const int lane = tid & 63;
    const int wv   = tid >> 6;          // wave 0..7, owns units wv*32..+31
    const int mm   = lane & 15;
    const int qq   = lane >> 4;

    // ---- W_hh residual frags resident: 4 ks x 3 gates x 2 halves = 96 regs ----
    i32x4 bwi[4][3][2];
    #pragma unroll
    for (int ks = 0; ks < 4; ++ks)
        #pragma unroll
        for (int g = 0; g < 3; ++g)
            #pragma unroll
            for (int h = 0; h < 2; ++h) {
                const int n = g * UNITS + wv * 32 + h * 16 + mm;
                bwi[ks][g][h] = *(const i32x4*)(wp8 +
                    ((size_t)(ks * G3) + n) * 64 + qq * 16);
            }
    short8 bwx[3][2];
    #pragma unroll
    for (int g = 0; g < 3; ++g)
        #pragma unroll
        for (int h = 0; h < 2; ++h)
            bwx[g][h] = *(const short8*)(wpx +
                ((size_t)(qq * G3) + g * UNITS + wv * 32 + h * 16 + mm) * 8);

    // ---- pre-stage ALL x for this WG's 4 batch rows (fp32 -> bf16) ----
    #pragma unroll
    for (int r = 0; r < MROWS; ++r) {
        const float4* src = (const float4*)(x_dyn + (size_t)(b0 + r) * XROW);
        short4s* dst = (short4s*)(xs + r * XROW);
        for (int i = tid; i < XROW / 4; i += 512) {
            const float4 v = src[i];
            short4s w;
            w.x = (short)f2bf(v.x); w.y = (short)f2bf(v.y);
            w.z = (short)f2bf(v.z); w.w = (short)f2bf(v.w);
            dst[i] = w;
        }
    }
    // zero both h buffers (h must be 0 at t=0)
    {
        int* az = (int*)A_s;
        for (int i = tid; i < 2 * MROWS * HP8 / 4; i += 512) az[i] = 0;
    }
    __syncthreads();

    // ---- cell mapping: lane (mm,qq) owns cells (batch row qq, units u0,u1).
    //      A rows GROUPED (arow = mm>>2): C rows 4qq..4qq+3 all = batch qq,
    //      so every acc element is identical -> element 0, no selects. ----
    const int u0 = wv * 32 + mm;
    const int u1 = u0 + 16;

    const float bfv[2] = { bias[u0],             bias[u1] };
    const float bov[2] = { bias[UNITS + u0],     bias[UNITS + u1] };
    const float bgv[2] = { bias[2 * UNITS + u0], bias[2 * UNITS + u1] };

    float ig[2], cc[2], hp[2];
    #pragma unroll
    for (int h = 0; h < 2; ++h) {
        const int u = h ? u1 : u0;
        float s = bias_s[u];
        #pragma unroll
        for (int j = 0; j < 27; ++j)
            s += x_sta[(b0 + qq) * 27 + j] * w_sh[j * UNITS + u];
        ig[h] = sigm_(s);
        cc[h] = 0.0f; hp[h] = 0.0f;
    }

    const int arow  = (mm >> 2);         // grouped A rows (broadcast across mm%4)
    const int abase = arow * HP8 + qq * 16;
    const unsigned short* xp = xs + (size_t)arow * XROW + qq * 8;
    const float SCL = 1.0f / (127.0f * 1024.0f);
    const f32x4 FZERO = {0.f, 0.f, 0.f, 0.f};
    const i32x4 IZERO = {0, 0, 0, 0};

    // ---- prologue: x-part of step 0 into FA; prefetch x(1) ----
    f32x4 FA[6], FB[6];
    short8 xa;
    {
        const short8 x0 = *(const short8*)(xp);
        FA[0] = MF(x0, bwx[0][0], FZERO);
        FA[1] = MF(x0, bwx[1][0], FZERO);
        FA[2] = MF(x0, bwx[2][0], FZERO);
        FA[3] = MF(x0, bwx[0][1], FZERO);
        FA[4] = MF(x0, bwx[1][1], FZERO);
        FA[5] = MF(x0, bwx[2][1], FZERO);
        xa = *(const short8*)(xp + 32);   // x(1)
    }

    // 365 steps = 182 unrolled pairs + final step (uses FA, no next)
    for (int i = 0; i < 182; ++i) {
        STEP_BODY(2 * i,     FA, FB, true);
        STEP_BODY(2 * i + 1, FB, FA, true);
    }
    STEP_BODY(364, FA, FB, false);

    out[(size_t)(b0 + qq) * UNITS + u0] = hp[0];
    out[(size_t)(b0 + qq) * UNITS + u1] = hp[1];
}

extern "C" void kernel_launch(void* const* d_in, const int* in_sizes, int n_in,
                              void* d_out, int out_size, void* d_ws, size_t ws_size,
                              hipStream_t stream) {
    const float* x_dyn  = (const float*)d_in[0];
    const float* x_sta  = (const float*)d_in[1];
    const float* w_ih   = (const float*)d_in[2];
    const float* w_hh   = (const float*)d_in[3];
    const float* w_sh   = (const float*)d_in[4];
    const float* bias   = (const float*)d_in[5];
    const float* bias_s = (const float*)d_in[6];
    float* out = (float*)d_out;
    signed char* wp8 = (signed char*)d_ws;                            // 196,608 B
    unsigned short* wpx = (unsigned short*)((char*)d_ws + WP8_BYTES); //  49,152 B

    pack_weights<<<((256 + 32) * G3 + 255) / 256, 256, 0, stream>>>(w_ih, w_hh, wp8, wpx);
    lstm_mfma<<<NWGS, 512, 0, stream>>>(x_dyn, x_sta, wp8, wpx, w_sh, bias, bias_s, out);
}

// Round 12
// 346.802 us; speedup vs baseline: 1.8160x; 1.0660x over previous
//
#include <hip/hip_runtime.h>

// EntityAwareLSTMLayer: B=1024, T=365, DYN=32, STATIC=27, U=256 (3U=768)
// Round 16: kill the x-GEMM's 4x M-duplication by batching 4 TIMESTEPS
//   into the MFMA M-dim (x is known ahead; only h is sequential).
//   - A-row m = (batch m>>2, t0+(m&3)) -> 6 bf16 MFMAs per 4-step WINDOW
//     (was 6/step): x-matrix 233 -> 58 cy/CU/step; x LDS reads /4.
//   - C layout: acc element e = timestep t0+e of batch qq -> tail uses
//     FC[g][E] with compile-time E (unrolled window; no dynamic indexing).
//   - FA/FB = window accs, ping-pong by window parity (48 regs, = R14).
//   - xs padded +96 shorts: window-91 A-frag overreads land in pad; garbage
//     only enters unused acc elements (e>=1 of the 1-step final window).
//   - Everything else = R15 (i8 W_hh, grouped A-rows/no selects, rcp tail,
//     2 waves/SIMD, 1 barrier/step).

typedef short short8 __attribute__((ext_vector_type(8)));
typedef short short4s __attribute__((ext_vector_type(4)));
typedef float f32x4 __attribute__((ext_vector_type(4)));
typedef int   i32x4 __attribute__((ext_vector_type(4)));

#define T_STEPS 365
#define UNITS   256
#define G3      768
#define MROWS   4
#define NWGS    256
#define HP8     288   // A row stride in BYTES (i8); 72 dw == 8 mod 32 -> 2-way free
#define XROW    (T_STEPS * 32)   // 11,680 shorts per batch row
#define XPAD    96               // covers window-91 overread (steps 365..367)
#define WP8_BYTES (256 * G3)     // 196,608: i8 W_hh residual frags

__device__ __forceinline__ unsigned short f2bf(float x) {
    union { float f; unsigned u; } v; v.f = x;
    return (unsigned short)((v.u + 0x7FFFu + ((v.u >> 16) & 1u)) >> 16);
}
__device__ __forceinline__ float rcp_(float x) {
    float r; asm("v_rcp_f32 %0, %1" : "=v"(r) : "v"(x)); return r;
}
__device__ __forceinline__ float sigm_(float x) {      // rcp(1+e^-x); rcp(inf)=0
    return rcp_(1.0f + __expf(-x));
}
__device__ __forceinline__ float tanh_(float x) {      // 1-2*rcp(1+e^2x)
    return 1.0f - 2.0f * rcp_(1.0f + __expf(2.0f * x));
}
__device__ __forceinline__ f32x4 MF(short8 a, short8 b, f32x4 c) {
    return __builtin_amdgcn_mfma_f32_16x16x32_bf16(a, b, c, 0, 0, 0);
}
__device__ __forceinline__ i32x4 MI(i32x4 a, i32x4 b, i32x4 c) {
    return __builtin_amdgcn_mfma_i32_16x16x64_i8(a, b, c, 0, 0, 0);
}

// Pack weights (identical to R12/R14/R15, validated):
//  - W_hh residual (k<256) -> i8 frags: (k,n) at wp8[((k>>6)*768+n)*64+(k&63)],
//    value rint(v*1024) clamped to +-127.
//  - W_ih -> bf16 frags: (kx,n) at wpx[((kx>>3)*768+n)*8+(kx&7)]
__global__ __launch_bounds__(256) void pack_weights(
    const float* __restrict__ w_ih, const float* __restrict__ w_hh,
    signed char* __restrict__ wp8, unsigned short* __restrict__ wpx)
{
    int idx = blockIdx.x * 256 + threadIdx.x;
    if (idx < 256 * G3) {
        const int k = idx / G3, n = idx - k * G3;
        float v = w_hh[k * G3 + n];
        if ((n & 255) == k) v -= 1.0f;   // subtract eye3 tile (identity exact in fp32)
        int q = (int)rintf(v * 1024.0f);
        q = q > 127 ? 127 : (q < -127 ? -127 : q);
        wp8[((size_t)((k >> 6) * G3) + n) * 64 + (k & 63)] = (signed char)q;
    } else if (idx < (256 + 32) * G3) {
        const int idx2 = idx - 256 * G3;
        const int kx = idx2 / G3, n = idx2 - kx * G3;
        wpx[((size_t)((kx >> 3) * G3) + n) * 8 + (kx & 7)] = f2bf(w_ih[kx * G3 + n]);
    }
}

// One timestep at window-offset E (compile-time 0..3). FC = this window's
// x-accs (element E = this step); FN = next window's accs, computed when
// DOX. W is the runtime window index (for the next-next x A-frag load).
#define STEP_BODY(E, FC, FN, DOX, LOADX, W) do {                              \
    const int p_ = (E) & 1;                                                   \
    __syncthreads();                                                          \
    const signed char* Ap_ = &A_s[p_][0][0];                                  \
    const i32x4 a0_ = *(const i32x4*)(Ap_ + abase);                           \
    const i32x4 a1_ = *(const i32x4*)(Ap_ + abase + 64);                      \
    const i32x4 a2_ = *(const i32x4*)(Ap_ + abase + 128);                     \
    const i32x4 a3_ = *(const i32x4*)(Ap_ + abase + 192);                     \
    /* h=0 chains complete first -> tail(h0) overlaps h1's matrix burst */    \
    i32x4 if0_ = MI(a0_, bwi[0][0][0], IZERO);                                \
    i32x4 io0_ = MI(a0_, bwi[0][1][0], IZERO);                                \
    i32x4 ig0_ = MI(a0_, bwi[0][2][0], IZERO);                                \
    if0_ = MI(a1_, bwi[1][0][0], if0_);                                       \
    io0_ = MI(a1_, bwi[1][1][0], io0_);                                       \
    ig0_ = MI(a1_, bwi[1][2][0], ig0_);                                       \
    if0_ = MI(a2_, bwi[2][0][0], if0_);                                       \
    io0_ = MI(a2_, bwi[2][1][0], io0_);                                       \
    ig0_ = MI(a2_, bwi[2][2][0], ig0_);                                       \
    if0_ = MI(a3_, bwi[3][0][0], if0_);                                       \
    io0_ = MI(a3_, bwi[3][1][0], io0_);                                       \
    ig0_ = MI(a3_, bwi[3][2][0], ig0_);                                       \
    i32x4 if1_ = MI(a0_, bwi[0][0][1], IZERO);                                \
    i32x4 io1_ = MI(a0_, bwi[0][1][1], IZERO);                                \
    i32x4 ig1_ = MI(a0_, bwi[0][2][1], IZERO);                                \
    if1_ = MI(a1_, bwi[1][0][1], if1_);                                       \
    io1_ = MI(a1_, bwi[1][1][1], io1_);                                       \
    ig1_ = MI(a1_, bwi[1][2][1], ig1_);                                       \
    if1_ = MI(a2_, bwi[2][0][1], if1_);                                       \
    io1_ = MI(a2_, bwi[2][1][1], io1_);                                       \
    ig1_ = MI(a2_, bwi[2][2][1], ig1_);                                       \
    if1_ = MI(a3_, bwi[3][0][1], if1_);                                       \
    io1_ = MI(a3_, bwi[3][1][1], io1_);                                       \
    ig1_ = MI(a3_, bwi[3][2][1], ig1_);                                       \
    if (DOX) {                                                                \
        /* next window's x-GEMM: 4 timesteps in M-dim, fills matrix pipe */   \
        const short8 xu_ = xa;                                                \
        FN[0] = MF(xu_, bwx[0][0], FZERO);                                    \
        FN[1] = MF(xu_, bwx[1][0], FZERO);                                    \
        FN[2] = MF(xu_, bwx[2][0], FZERO);                                    \
        FN[3] = MF(xu_, bwx[0][1], FZERO);                                    \
        FN[4] = MF(xu_, bwx[1][1], FZERO);                                    \
        FN[5] = MF(xu_, bwx[2][1], FZERO);                                    \
        if (LOADX)                                                            \
            xa = *(const short8*)(xq + (size_t)((W) + 2) * 128);              \
    }                                                                         \
    {   /* tail h=0: x-part element E, i8-part element 0 (duplicated) */      \
        const float bh_ = hp[0];                                              \
        const float gf_ = FC[0][E] + bfv[0] + bh_ + (float)if0_[0] * SCL;     \
        const float go_ = FC[1][E] + bov[0] + bh_ + (float)io0_[0] * SCL;     \
        const float gg_ = FC[2][E] + bgv[0] + bh_ + (float)ig0_[0] * SCL;     \
        const float f_  = sigm_(gf_);                                         \
        const float o_  = sigm_(go_);                                         \
        const float gt_ = tanh_(gg_);                                         \
        const float cn_ = f_ * cc[0] + ig[0] * gt_;                           \
        cc[0] = cn_;                                                          \
        const float hn_ = o_ * tanh_(cn_);                                    \
        hp[0] = hn_;                                                          \
        A_s[p_ ^ 1][qq][u0] = (signed char)__float2int_rn(hn_ * 127.0f);      \
    }                                                                         \
    {   /* tail h=1 */                                                        \
        const float bh_ = hp[1];                                              \
        const float gf_ = FC[3][E] + bfv[1] + bh_ + (float)if1_[0] * SCL;     \
        const float go_ = FC[4][E] + bov[1] + bh_ + (float)io1_[0] * SCL;     \
        const float gg_ = FC[5][E] + bgv[1] + bh_ + (float)ig1_[0] * SCL;     \
        const float f_  = sigm_(gf_);                                         \
        const float o_  = sigm_(go_);                                         \
        const float gt_ = tanh_(gg_);                                         \
        const float cn_ = f_ * cc[1] + ig[1] * gt_;                           \
        cc[1] = cn_;                                                          \
        const float hn_ = o_ * tanh_(cn_);                                    \
        hp[1] = hn_;                                                          \
        A_s[p_ ^ 1][qq][u1] = (signed char)__float2int_rn(hn_ * 127.0f);      \
    }                                                                         \
} while (0)

// 4-step window W: steps 4W..4W+3, x-accs FC; xstep (E=1) computes FN.
#define WINDOW4(W, FC, FN, LOADX) do {                                        \
    STEP_BODY(0, FC, FN, false, false, W);                                    \
    STEP_BODY(1, FC, FN, true,  LOADX, W);                                    \
    STEP_BODY(2, FC, FN, false, false, W);                                    \
    STEP_BODY(3, FC, FN, false, false, W);                                    \
} while (0)

__global__ __launch_bounds__(512, 2) void lstm_mfma(
    const float* __restrict__ x_dyn,   // [1024][365][32]
    const float* __restrict__ x_sta,   // [1024][27]
    const signed char* __restrict__ wp8,    // i8 W_hh residual frags
    const unsigned short* __restrict__ wpx, // bf16 W_ih frags
    const float* __restrict__ w_sh,    // [27][256]
    const float* __restrict__ bias,    // [768]
    const float* __restrict__ bias_s,  // [256]
    float* __restrict__ out)           // [1024][256]
{
    __shared__ signed char A_s[2][MROWS][HP8];        // 2,304 B (h as i8, dbuf)
    __shared__ unsigned short xs[MROWS * XROW + XPAD]; // 93,632 B (all x, bf16)

    const int tid  = threadIdx.x;
    const int b0   = blockIdx.x * MROWS;
    const int lane = tid & 63;
    const int wv   = tid >> 6;          // wave 0..7, owns units wv*32..+31
    const int mm   = lane & 15;
    const int qq   = lane >> 4;

    // ---- W_hh residual frags resident: 4 ks x 3 gates x 2 halves = 96 regs ----
    i32x4 bwi[4][3][2];
    #pragma unroll
    for (int ks = 0; ks < 4; ++ks)
        #pragma unroll
        for (int g = 0; g < 3; ++g)
            #pragma unroll
            for (int h = 0; h < 2; ++h) {
                const int n = g * UNITS + wv * 32 + h * 16 + mm;
                bwi[ks][g][h] = *(const i32x4*)(wp8 +
                    ((size_t)(ks * G3) + n) * 64 + qq * 16);
            }
    short8 bwx[3][2];
    #pragma unroll
    for (int g = 0; g < 3; ++g)
        #pragma unroll
        for (int h = 0; h < 2; ++h)
            bwx[g][h] = *(const short8*)(wpx +
                ((size_t)(qq * G3) + g * UNITS + wv * 32 + h * 16 + mm) * 8);

    // ---- pre-stage ALL x for this WG's 4 batch rows (fp32 -> bf16) ----
    #pragma unroll
    for (int r = 0; r < MROWS; ++r) {
        const float4* src = (const float4*)(x_dyn + (size_t)(b0 + r) * XROW);
        short4s* dst = (short4s*)(xs + r * XROW);
        for (int i = tid; i < XROW / 4; i += 512) {
            const float4 v = src[i];
            short4s w;
            w.x = (short)f2bf(v.x); w.y = (short)f2bf(v.y);
            w.z = (short)f2bf(v.z); w.w = (short)f2bf(v.w);
            dst[i] = w;
        }
    }
    // zero the pad (window-91 overread) and both h buffers
    if (tid < XPAD / 2) ((int*)(xs + MROWS * XROW))[tid] = 0;
    {
        int* az = (int*)A_s;
        for (int i = tid; i < 2 * MROWS * HP8 / 4; i += 512) az[i] = 0;
    }
    __syncthreads();

    // ---- cell mapping: lane (mm,qq) owns cells (batch row qq, units u0,u1).
    //      h A-rows GROUPED (arow = mm>>2): i8 acc elements all identical.
    //      x A-rows = (batch mm>>2, t0 + (mm&3)): acc element e = timestep. ----
    const int u0 = wv * 32 + mm;
    const int u1 = u0 + 16;

    const float bfv[2] = { bias[u0],             bias[u1] };
    const float bov[2] = { bias[UNITS + u0],     bias[UNITS + u1] };
    const float bgv[2] = { bias[2 * UNITS + u0], bias[2 * UNITS + u1] };

    float ig[2], cc[2], hp[2];
    #pragma unroll
    for (int h = 0; h < 2; ++h) {
        const int u = h ? u1 : u0;
        float s = bias_s[u];
        #pragma unroll
        for (int j = 0; j < 27; ++j)
            s += x_sta[(b0 + qq) * 27 + j] * w_sh[j * UNITS + u];
        ig[h] = sigm_(s);
        cc[h] = 0.0f; hp[h] = 0.0f;
    }

    const int abase = (mm >> 2) * HP8 + qq * 16;        // grouped h A-read
    // x A-frag source: row (batch mm>>2, timestep t0+(mm&3)), k-slice qq*8
    const unsigned short* xq = xs + (size_t)(mm >> 2) * XROW + (mm & 3) * 32 + qq * 8;
    const float SCL = 1.0f / (127.0f * 1024.0f);
    const f32x4 FZERO = {0.f, 0.f, 0.f, 0.f};
    const i32x4 IZERO = {0, 0, 0, 0};

    // ---- prologue: window 0 accs into FA; prefetch window-1 x A-frag ----
    f32x4 FA[6], FB[6];
    short8 xa;
    {
        const short8 x0 = *(const short8*)(xq);
        FA[0] = MF(x0, bwx[0][0], FZERO);
        FA[1] = MF(x0, bwx[1][0], FZERO);
        FA[2] = MF(x0, bwx[2][0], FZERO);
        FA[3] = MF(x0, bwx[0][1], FZERO);
        FA[4] = MF(x0, bwx[1][1], FZERO);
        FA[5] = MF(x0, bwx[2][1], FZERO);
        xa = *(const short8*)(xq + 128);   // window 1
    }

    // windows 0..89 in ping-pong pairs, window 90, then final step 364
    for (int wp = 0; wp < 45; ++wp) {
        const int w0 = wp * 2;
        WINDOW4(w0,     FA, FB, true);
        WINDOW4(w0 + 1, FB, FA, true);
    }
    WINDOW4(90, FA, FB, false);            // computes FB for window 91 (step 364)
    STEP_BODY(0, FB, FA, false, false, 91);

    out[(size_t)(b0 + qq) * UNITS + u0] = hp[0];
    out[(size_t)(b0 + qq) * UNITS + u1] = hp[1];
}

extern "C" void kernel_launch(void* const* d_in, const int* in_sizes, int n_in,
                              void* d_out, int out_size, void* d_ws, size_t ws_size,
                              hipStream_t stream) {
    const float* x_dyn  = (const float*)d_in[0];
    const float* x_sta  = (const float*)d_in[1];
    const float* w_ih   = (const float*)d_in[2];
    const float* w_hh   = (const float*)d_in[3];
    const float* w_sh   = (const float*)d_in[4];
    const float* bias   = (const float*)d_in[5];
    const float* bias_s = (const float*)d_in[6];
    float* out = (float*)d_out;
    signed char* wp8 = (signed char*)d_ws;                            // 196,608 B
    unsigned short* wpx = (unsigned short*)((char*)d_ws + WP8_BYTES); //  49,152 B

    pack_weights<<<((256 + 32) * G3 + 255) / 256, 256, 0, stream>>>(w_ih, w_hh, wp8, wpx);
    lstm_mfma<<<NWGS, 512, 0, stream>>>(x_dyn, x_sta, wp8, wpx, w_sh, bias, bias_s, out);
}